// Round 9
// baseline (172.967 us; speedup 1.0000x reference)
//
#include <hip/hip_runtime.h>

#define CIN 64
#define COUT 96
#define HW_  1024
#define PPB 16
#define NTHR 512
#define NITER 5
#define NMF_EPS 1e-20f

// __launch_bounds__(512, 2): 2 waves/EU min -> 256-VGPR cap. The ~200-float
// live set (wreg[96]+wcol[64]+working) MUST stay in registers; the default
// heuristic capped at 128 VGPRs and spilled 160 floats/thread to scratch
// (256 MB FETCH per dispatch, 172 us — round 8).
__global__ __launch_bounds__(NTHR, 2) void nmf_kernel(
    const float* __restrict__ x,
    const float* __restrict__ w,
    const float* __restrict__ h0,
    float* __restrict__ out)
{
    __shared__ float  Hs[PPB][COUT + 4];  // [p][j], row = 100 floats (400B, 16B-aligned)
    __shared__ float  Tsp[CIN][20];       // [i][p], row = 20 floats (80B, 16B-aligned)
    __shared__ float4 Par[8];             // per-wave partial sums (4 px each)

    const int t = threadIdx.x;
    const int tile = blockIdx.x;
    const int b = tile >> 6;              // 4 batches * 64 tiles
    const int hw0 = (tile & 63) << 4;     // 16 pixels per tile

    // stage-1 identity: thread = (i-row, pixel-pair); wave-uniform ppair -> Hs reads broadcast
    const int i1 = t & 63;
    const int p0 = (t >> 6) << 1;
    // stage-2 identity: thread = (j-lane, pixel-quad); wave-uniform pq -> Tsp reads broadcast
    const int jr = t & 127;               // j, active if < 96
    const int pq = t >> 7;                // 0..3 (4 px each)
    const int wv = t >> 6;                // wave id 0..7; waves (2k,2k+1) pair on pq=k
    const bool act = (jr < COUT);

    // ---- one-time: h init ----
    for (int k = t; k < PPB * COUT; k += NTHR) {
        const int p = k & 15;
        const int j = k >> 4;
        Hs[p][j] = h0[j];
    }

    // ---- one-time: W row i1 -> wreg[96] (stage 1) ----
    float wreg[COUT];
    #pragma unroll
    for (int j = 0; j < COUT; j += 4) {
        const float4 v = *(const float4*)&w[i1 * COUT + j];
        wreg[j] = v.x; wreg[j + 1] = v.y; wreg[j + 2] = v.z; wreg[j + 3] = v.w;
    }
    // ---- one-time: W column jr -> wcol[64] (stage 2) ----
    float wcol[CIN];
    #pragma unroll
    for (int i = 0; i < CIN; ++i) wcol[i] = act ? w[i * COUT + jr] : 0.f;

    // x for this thread's two stage-1 pixels
    const float* xb = x + (size_t)b * CIN * HW_ + hw0;
    const float x0 = xb[(size_t)i1 * HW_ + p0];
    const float x1 = xb[(size_t)i1 * HW_ + p0 + 1];

    __syncthreads();

    #pragma unroll 1
    for (int it = 0; it < NITER; ++it) {
        // ---- stage 1: denom[p][i] = eps + sum_j h[p][j]*W[i][j]; Tsp[i][p] = x/denom ----
        float a0 = 0.f, a1 = 0.f, a2 = 0.f, a3 = 0.f;
        float c0 = 0.f, c1 = 0.f, c2 = 0.f, c3 = 0.f;
        #pragma unroll
        for (int j = 0; j < COUT; j += 4) {
            const float4 hv0 = *(const float4*)&Hs[p0][j];       // broadcast b128
            const float4 hv1 = *(const float4*)&Hs[p0 + 1][j];   // broadcast b128
            a0 += wreg[j] * hv0.x;     a1 += wreg[j + 1] * hv0.y;
            a2 += wreg[j + 2] * hv0.z; a3 += wreg[j + 3] * hv0.w;
            c0 += wreg[j] * hv1.x;     c1 += wreg[j + 1] * hv1.y;
            c2 += wreg[j + 2] * hv1.z; c3 += wreg[j + 3] * hv1.w;
        }
        const float d0 = ((a0 + a1) + (a2 + a3)) + NMF_EPS;
        const float d1 = ((c0 + c1) + (c2 + c3)) + NMF_EPS;
        float2 tw; tw.x = x0 / d0; tw.y = x1 / d1;
        *(float2*)&Tsp[i1][p0] = tw;
        __syncthreads();   // Tsp ready

        // ---- stage 2: u[px] = sum_i W[i][jr] * t[px][i] for px = 4*pq..4*pq+3 ----
        float u0 = 0.f, u1 = 0.f, u2 = 0.f, u3 = 0.f;
        #pragma unroll
        for (int i = 0; i < CIN; ++i) {
            const float4 tv = *(const float4*)&Tsp[i][pq * 4];   // broadcast b128
            u0 += wcol[i] * tv.x; u1 += wcol[i] * tv.y;
            u2 += wcol[i] * tv.z; u3 += wcol[i] * tv.w;
        }
        float hp0 = 0.f, hp1 = 0.f, hp2 = 0.f, hp3 = 0.f;
        if (act) {
            hp0 = Hs[pq * 4 + 0][jr] * (1.f + u0);
            hp1 = Hs[pq * 4 + 1][jr] * (1.f + u1);
            hp2 = Hs[pq * 4 + 2][jr] * (1.f + u2);
            hp3 = Hs[pq * 4 + 3][jr] * (1.f + u3);
        }
        // ---- normalize: per-px sum over all 96 j (64-lane tree + cross-wave pair) ----
        float s0 = hp0, s1 = hp1, s2 = hp2, s3 = hp3;
        #pragma unroll
        for (int d = 32; d >= 1; d >>= 1) {
            s0 += __shfl_xor(s0, d, 64);
            s1 += __shfl_xor(s1, d, 64);
            s2 += __shfl_xor(s2, d, 64);
            s3 += __shfl_xor(s3, d, 64);
        }
        if ((t & 63) == 0) Par[wv] = make_float4(s0, s1, s2, s3);
        __syncthreads();   // Par ready
        const float4 other = Par[wv ^ 1];                        // broadcast
        const float inv0 = 1.f / ((s0 + other.x) + NMF_EPS);
        const float inv1 = 1.f / ((s1 + other.y) + NMF_EPS);
        const float inv2 = 1.f / ((s2 + other.z) + NMF_EPS);
        const float inv3 = 1.f / ((s3 + other.w) + NMF_EPS);
        if (act) {
            Hs[pq * 4 + 0][jr] = hp0 * inv0;
            Hs[pq * 4 + 1][jr] = hp1 * inv1;
            Hs[pq * 4 + 2][jr] = hp2 * inv2;
            Hs[pq * 4 + 3][jr] = hp3 * inv3;
        }
        __syncthreads();   // Hs ready for next iteration
    }

    // ---- write h -> out (B, Cout, H, W) ----
    for (int k = t; k < PPB * COUT; k += NTHR) {
        const int p = k & 15;
        const int j = k >> 4;
        out[(size_t)b * COUT * HW_ + (size_t)j * HW_ + hw0 + p] = Hs[p][j];
    }
}

extern "C" void kernel_launch(void* const* d_in, const int* in_sizes, int n_in,
                              void* d_out, int out_size, void* d_ws, size_t ws_size,
                              hipStream_t stream) {
    const float* x  = (const float*)d_in[0];
    const float* w  = (const float*)d_in[1];
    const float* h0 = (const float*)d_in[2];
    float* out = (float*)d_out;
    nmf_kernel<<<256, NTHR, 0, stream>>>(x, w, h0, out);
}

// Round 12
// 169.941 us; speedup vs baseline: 1.0178x; 1.0178x over previous
//
#include <hip/hip_runtime.h>

#define CIN 64
#define COUT 96
#define HW_  1024
#define PPB 16
#define NTHR 512
#define NITER 5
#define NMF_EPS 1e-20f

typedef float f32x16 __attribute__((ext_vector_type(16)));

// W row/column held in NAMED ext_vector SSA values (not arrays!). float
// arrays of 96/64 elements exceed the promote-alloca limit and get lowered
// to scratch (rounds 8-9: 256 MB FETCH/dispatch, 172 us, launch_bounds had
// no effect because the spill was an alloca decision, not a budget one).
#define LOAD_WROW(V, JB) do {                                              \
    const float4* wp_ = (const float4*)&w[i1 * COUT + (JB)];               \
    const float4 t0_ = wp_[0], t1_ = wp_[1], t2_ = wp_[2], t3_ = wp_[3];   \
    V = (f32x16){t0_.x, t0_.y, t0_.z, t0_.w, t1_.x, t1_.y, t1_.z, t1_.w,  \
                 t2_.x, t2_.y, t2_.z, t2_.w, t3_.x, t3_.y, t3_.z, t3_.w}; \
} while (0)

#define S1_BLOCK(V, JB)                                                    \
    _Pragma("unroll") for (int e = 0; e < 16; e += 4) {                    \
        const float4 hv0 = *(const float4*)&Hs[p0][(JB) + e];              \
        const float4 hv1 = *(const float4*)&Hs[p0 + 1][(JB) + e];          \
        a0 += V[e] * hv0.x;     a1 += V[e + 1] * hv0.y;                    \
        a2 += V[e + 2] * hv0.z; a3 += V[e + 3] * hv0.w;                    \
        c0 += V[e] * hv1.x;     c1 += V[e + 1] * hv1.y;                    \
        c2 += V[e + 2] * hv1.z; c3 += V[e + 3] * hv1.w;                    \
    }

#define S2_BLOCK(V, IB)                                                    \
    _Pragma("unroll") for (int e = 0; e < 16; ++e) {                       \
        const float4 tv = *(const float4*)&Tsp[(IB) + e][pq4];             \
        u0 += V[e] * tv.x; u1 += V[e] * tv.y;                              \
        u2 += V[e] * tv.z; u3 += V[e] * tv.w;                              \
    }

__global__ __launch_bounds__(NTHR, 2) void nmf_kernel(
    const float* __restrict__ x,
    const float* __restrict__ w,
    const float* __restrict__ h0,
    float* __restrict__ out)
{
    __shared__ float  Hs[PPB][COUT + 4];  // [p][j], row = 100 floats (400B, 16B-aligned)
    __shared__ float  Tsp[CIN][20];       // [i][p], row = 20 floats (80B, 16B-aligned)
    __shared__ float4 Par[8];             // per-wave partial sums (4 px each)

    const int t = threadIdx.x;
    const int tile = blockIdx.x;
    const int b = tile >> 6;              // 4 batches * 64 tiles
    const int hw0 = (tile & 63) << 4;     // 16 pixels per tile

    // stage-1 identity: thread = (i-row, pixel-pair); wave-uniform ppair -> Hs reads broadcast
    const int i1 = t & 63;
    const int p0 = (t >> 6) << 1;
    // stage-2 identity: thread = (j-lane, pixel-quad); wave-uniform pq -> Tsp reads broadcast
    const int jr = t & 127;               // j, active if < 96
    const int pq = t >> 7;                // 0..3 (4 px each)
    const int pq4 = pq * 4;
    const int wv = t >> 6;                // wave id 0..7; waves (2k,2k+1) pair on pq=k
    const bool act = (jr < COUT);

    // ---- one-time: h init ----
    for (int k = t; k < PPB * COUT; k += NTHR) {
        const int p = k & 15;
        const int j = k >> 4;
        Hs[p][j] = h0[j];
    }

    // ---- one-time: W row i1 -> wr0..wr5 (stage 1, 96 floats in registers) ----
    f32x16 wr0, wr1, wr2, wr3, wr4, wr5;
    LOAD_WROW(wr0, 0);  LOAD_WROW(wr1, 16); LOAD_WROW(wr2, 32);
    LOAD_WROW(wr3, 48); LOAD_WROW(wr4, 64); LOAD_WROW(wr5, 80);

    // ---- one-time: W column jr -> wc0..wc3 (stage 2, 64 floats in registers) ----
    f32x16 wc0, wc1, wc2, wc3;
    #pragma unroll
    for (int e = 0; e < 16; ++e) {
        wc0[e] = act ? w[(e)      * COUT + jr] : 0.f;
        wc1[e] = act ? w[(e + 16) * COUT + jr] : 0.f;
        wc2[e] = act ? w[(e + 32) * COUT + jr] : 0.f;
        wc3[e] = act ? w[(e + 48) * COUT + jr] : 0.f;
    }

    // x for this thread's two stage-1 pixels
    const float* xb = x + (size_t)b * CIN * HW_ + hw0;
    const float x0 = xb[(size_t)i1 * HW_ + p0];
    const float x1 = xb[(size_t)i1 * HW_ + p0 + 1];

    __syncthreads();

    #pragma unroll 1
    for (int it = 0; it < NITER; ++it) {
        // ---- stage 1: denom[p][i] = eps + sum_j h[p][j]*W[i][j]; Tsp[i][p] = x/denom ----
        float a0 = 0.f, a1 = 0.f, a2 = 0.f, a3 = 0.f;
        float c0 = 0.f, c1 = 0.f, c2 = 0.f, c3 = 0.f;
        S1_BLOCK(wr0, 0)  S1_BLOCK(wr1, 16) S1_BLOCK(wr2, 32)
        S1_BLOCK(wr3, 48) S1_BLOCK(wr4, 64) S1_BLOCK(wr5, 80)
        const float d0 = ((a0 + a1) + (a2 + a3)) + NMF_EPS;
        const float d1 = ((c0 + c1) + (c2 + c3)) + NMF_EPS;
        float2 tw; tw.x = x0 / d0; tw.y = x1 / d1;
        *(float2*)&Tsp[i1][p0] = tw;
        __syncthreads();   // Tsp ready

        // ---- stage 2: u[px] = sum_i W[i][jr] * t[px][i] for px = pq4..pq4+3 ----
        float u0 = 0.f, u1 = 0.f, u2 = 0.f, u3 = 0.f;
        S2_BLOCK(wc0, 0)  S2_BLOCK(wc1, 16)
        S2_BLOCK(wc2, 32) S2_BLOCK(wc3, 48)
        float hp0 = 0.f, hp1 = 0.f, hp2 = 0.f, hp3 = 0.f;
        if (act) {
            hp0 = Hs[pq4 + 0][jr] * (1.f + u0);
            hp1 = Hs[pq4 + 1][jr] * (1.f + u1);
            hp2 = Hs[pq4 + 2][jr] * (1.f + u2);
            hp3 = Hs[pq4 + 3][jr] * (1.f + u3);
        }
        // ---- normalize: per-px sum over all 96 j (64-lane tree + cross-wave pair) ----
        float s0 = hp0, s1 = hp1, s2 = hp2, s3 = hp3;
        #pragma unroll
        for (int d = 32; d >= 1; d >>= 1) {
            s0 += __shfl_xor(s0, d, 64);
            s1 += __shfl_xor(s1, d, 64);
            s2 += __shfl_xor(s2, d, 64);
            s3 += __shfl_xor(s3, d, 64);
        }
        if ((t & 63) == 0) Par[wv] = make_float4(s0, s1, s2, s3);
        __syncthreads();   // Par ready
        const float4 other = Par[wv ^ 1];                        // broadcast
        const float inv0 = 1.f / ((s0 + other.x) + NMF_EPS);
        const float inv1 = 1.f / ((s1 + other.y) + NMF_EPS);
        const float inv2 = 1.f / ((s2 + other.z) + NMF_EPS);
        const float inv3 = 1.f / ((s3 + other.w) + NMF_EPS);
        if (act) {
            Hs[pq4 + 0][jr] = hp0 * inv0;
            Hs[pq4 + 1][jr] = hp1 * inv1;
            Hs[pq4 + 2][jr] = hp2 * inv2;
            Hs[pq4 + 3][jr] = hp3 * inv3;
        }
        __syncthreads();   // Hs ready for next iteration
    }

    // ---- write h -> out (B, Cout, H, W) ----
    for (int k = t; k < PPB * COUT; k += NTHR) {
        const int p = k & 15;
        const int j = k >> 4;
        out[(size_t)b * COUT * HW_ + (size_t)j * HW_ + hw0 + p] = Hs[p][j];
    }
}

extern "C" void kernel_launch(void* const* d_in, const int* in_sizes, int n_in,
                              void* d_out, int out_size, void* d_ws, size_t ws_size,
                              hipStream_t stream) {
    const float* x  = (const float*)d_in[0];
    const float* w  = (const float*)d_in[1];
    const float* h0 = (const float*)d_in[2];
    float* out = (float*)d_out;
    nmf_kernel<<<256, NTHR, 0, stream>>>(x, w, h0, out);
}

// Round 13
// 86.771 us; speedup vs baseline: 1.9934x; 1.9585x over previous
//
#include <hip/hip_runtime.h>

#define CIN 64
#define COUT 96
#define HW_  1024
#define PPB 16
#define NTHR 512
#define NITER 5
#define NMF_EPS 1e-20f

typedef float f32x16 __attribute__((ext_vector_type(16)));

// Register budget lesson (rounds 8-12): the allocator targets 128 VGPRs for
// this kernel shape and will spill rather than exceed it (launch_bounds and
// ext-vector SSA both failed to lift it). So: stage-1 W row (96 floats) in
// registers -- that fits (round 5 ran 28us) -- and stage-2 W stays in LDS,
// read conflict-free (lanes = consecutive j, stride-1, 2 lanes/bank = free).
#define LOAD_WROW(V, JB) do {                                              \
    const float4* wp_ = (const float4*)&w[i1 * COUT + (JB)];               \
    const float4 t0_ = wp_[0], t1_ = wp_[1], t2_ = wp_[2], t3_ = wp_[3];   \
    V = (f32x16){t0_.x, t0_.y, t0_.z, t0_.w, t1_.x, t1_.y, t1_.z, t1_.w,  \
                 t2_.x, t2_.y, t2_.z, t2_.w, t3_.x, t3_.y, t3_.z, t3_.w}; \
} while (0)

#define S1_BLOCK(V, JB)                                                    \
    _Pragma("unroll") for (int e = 0; e < 16; e += 4) {                    \
        const float4 hv0 = *(const float4*)&Hs[p0][(JB) + e];              \
        const float4 hv1 = *(const float4*)&Hs[p0 + 1][(JB) + e];          \
        a0 += V[e] * hv0.x;     a1 += V[e + 1] * hv0.y;                    \
        a2 += V[e + 2] * hv0.z; a3 += V[e + 3] * hv0.w;                    \
        c0 += V[e] * hv1.x;     c1 += V[e + 1] * hv1.y;                    \
        c2 += V[e + 2] * hv1.z; c3 += V[e + 3] * hv1.w;                    \
    }

__global__ __launch_bounds__(NTHR) void nmf_kernel(
    const float* __restrict__ x,
    const float* __restrict__ w,
    const float* __restrict__ h0,
    float* __restrict__ out)
{
    __shared__ float  Wr[CIN][COUT];      // [i][j], row = 96 floats; stage-2 reads
                                          // lane=jr consecutive -> stride-1, conflict-free
    __shared__ float  Hs[PPB][COUT + 4];  // [p][j], row = 100 floats (400B, 16B-aligned)
    __shared__ float  Tsp[CIN][20];       // [i][p], row = 20 floats (80B)
    __shared__ float4 Par[8];             // per-wave partial sums (4 px each)

    const int t = threadIdx.x;
    const int tile = blockIdx.x;
    const int b = tile >> 6;              // 4 batches * 64 tiles
    const int hw0 = (tile & 63) << 4;     // 16 pixels per tile

    // stage-1 identity: thread = (i-row, pixel-pair); wave-uniform ppair -> Hs reads broadcast
    const int i1 = t & 63;
    const int p0 = (t >> 6) << 1;
    // stage-2 identity: thread = (j-lane, pixel-quad); wave-uniform pq -> Tsp reads broadcast
    const int jr = t & 127;               // j, active if < 96
    const int pq4 = (t >> 7) << 2;        // pixel-quad base 0/4/8/12
    const int wv = t >> 6;                // wave id 0..7
    const bool act = (jr < COUT);
    const int jrc = act ? jr : 0;         // clamped for safe LDS reads on idle lanes

    // ---- one-time staging ----
    for (int k = t; k < CIN * COUT; k += NTHR) {   // Wr <- w (coalesced, same layout)
        ((float*)Wr)[k] = w[k];
    }
    for (int k = t; k < PPB * COUT; k += NTHR) {   // h init
        const int p = k & 15;
        const int j = k >> 4;
        Hs[p][j] = h0[j];
    }

    // ---- one-time: W row i1 -> wr0..wr5 (stage 1, 96 floats in registers) ----
    f32x16 wr0, wr1, wr2, wr3, wr4, wr5;
    LOAD_WROW(wr0, 0);  LOAD_WROW(wr1, 16); LOAD_WROW(wr2, 32);
    LOAD_WROW(wr3, 48); LOAD_WROW(wr4, 64); LOAD_WROW(wr5, 80);

    // x for this thread's two stage-1 pixels
    const float* xb = x + (size_t)b * CIN * HW_ + hw0;
    const float x0 = xb[(size_t)i1 * HW_ + p0];
    const float x1 = xb[(size_t)i1 * HW_ + p0 + 1];

    __syncthreads();

    #pragma unroll 1
    for (int it = 0; it < NITER; ++it) {
        // ---- stage 1: denom[p][i] = eps + sum_j h[p][j]*W[i][j]; Tsp[i][p] = x/denom ----
        float a0 = 0.f, a1 = 0.f, a2 = 0.f, a3 = 0.f;
        float c0 = 0.f, c1 = 0.f, c2 = 0.f, c3 = 0.f;
        S1_BLOCK(wr0, 0)  S1_BLOCK(wr1, 16) S1_BLOCK(wr2, 32)
        S1_BLOCK(wr3, 48) S1_BLOCK(wr4, 64) S1_BLOCK(wr5, 80)
        const float d0 = ((a0 + a1) + (a2 + a3)) + NMF_EPS;
        const float d1 = ((c0 + c1) + (c2 + c3)) + NMF_EPS;
        float2 tw; tw.x = x0 / d0; tw.y = x1 / d1;
        *(float2*)&Tsp[i1][p0] = tw;
        __syncthreads();   // Tsp ready

        // ---- stage 2: u[px] = sum_i W[i][jr] * t[px][i] for px = pq4..pq4+3 ----
        float u0 = 0.f, u1 = 0.f, u2 = 0.f, u3 = 0.f;
        #pragma unroll
        for (int i = 0; i < CIN; ++i) {
            const float wv_ = Wr[i][jrc];                        // stride-1, conflict-free
            const float4 tv = *(const float4*)&Tsp[i][pq4];      // broadcast b128
            u0 += wv_ * tv.x; u1 += wv_ * tv.y;
            u2 += wv_ * tv.z; u3 += wv_ * tv.w;
        }
        float hp0 = 0.f, hp1 = 0.f, hp2 = 0.f, hp3 = 0.f;
        if (act) {
            hp0 = Hs[pq4 + 0][jr] * (1.f + u0);
            hp1 = Hs[pq4 + 1][jr] * (1.f + u1);
            hp2 = Hs[pq4 + 2][jr] * (1.f + u2);
            hp3 = Hs[pq4 + 3][jr] * (1.f + u3);
        }
        // ---- normalize: per-px sum over all 96 j (64-lane tree + cross-wave pair) ----
        float s0 = hp0, s1 = hp1, s2 = hp2, s3 = hp3;
        #pragma unroll
        for (int d = 32; d >= 1; d >>= 1) {
            s0 += __shfl_xor(s0, d, 64);
            s1 += __shfl_xor(s1, d, 64);
            s2 += __shfl_xor(s2, d, 64);
            s3 += __shfl_xor(s3, d, 64);
        }
        if ((t & 63) == 0) Par[wv] = make_float4(s0, s1, s2, s3);
        __syncthreads();   // Par ready
        const float4 other = Par[wv ^ 1];                        // broadcast
        const float inv0 = 1.f / ((s0 + other.x) + NMF_EPS);
        const float inv1 = 1.f / ((s1 + other.y) + NMF_EPS);
        const float inv2 = 1.f / ((s2 + other.z) + NMF_EPS);
        const float inv3 = 1.f / ((s3 + other.w) + NMF_EPS);
        if (act) {
            Hs[pq4 + 0][jr] = hp0 * inv0;
            Hs[pq4 + 1][jr] = hp1 * inv1;
            Hs[pq4 + 2][jr] = hp2 * inv2;
            Hs[pq4 + 3][jr] = hp3 * inv3;
        }
        __syncthreads();   // Hs ready for next iteration
    }

    // ---- write h -> out (B, Cout, H, W) ----
    for (int k = t; k < PPB * COUT; k += NTHR) {
        const int p = k & 15;
        const int j = k >> 4;
        out[(size_t)b * COUT * HW_ + (size_t)j * HW_ + hw0 + p] = Hs[p][j];
    }
}

extern "C" void kernel_launch(void* const* d_in, const int* in_sizes, int n_in,
                              void* d_out, int out_size, void* d_ws, size_t ws_size,
                              hipStream_t stream) {
    const float* x  = (const float*)d_in[0];
    const float* w  = (const float*)d_in[1];
    const float* h0 = (const float*)d_in[2];
    float* out = (float*)d_out;
    nmf_kernel<<<256, NTHR, 0, stream>>>(x, w, h0, out);
}

// Round 14
// 28.390 us; speedup vs baseline: 6.0925x; 3.0564x over previous
//
#include <hip/hip_runtime.h>

#define CIN 64
#define COUT 96
#define HW_  1024
#define PPB 16
#define NTHR 512
#define NITER 5
#define NMF_EPS 1e-20f

// Register rule learned rounds 8-13: allocator pins this shape at 128 VGPRs
// and spills anything bigger (arrays, ext-vectors, launch_bounds all failed
// to lift it). So per-thread W storage is HALVED: 48 floats (j-half of row),
// partial denominators combined via LDS. Total live set ~80 floats.
__global__ __launch_bounds__(NTHR) void nmf_kernel(
    const float* __restrict__ x,
    const float* __restrict__ w,
    const float* __restrict__ h0,
    float* __restrict__ out)
{
    __shared__ float  Wr[CIN][COUT];       // [i][j] 24KB; stage-2 stride-1 reads
    __shared__ float  Hst[COUT][20];       // [j][p] 7.7KB; rows 80B -> b128 lane-stride 5 quads, conflict-free
    __shared__ float  Tsp[CIN][20];        // [i][p] 5.1KB
    __shared__ float  Dpart[2][CIN][20];   // per-half partial denoms, 10.2KB
    __shared__ float4 Par[8];              // per-wave normalize partials

    const int t = threadIdx.x;
    const int tile = blockIdx.x;
    const int b = tile >> 6;               // 4 batches * 64 tiles
    const int hw0 = (tile & 63) << 4;      // 16 px per tile

    // stage-1 identity: (i-row, j-half, pixel-quad) — all wave-uniform except i1
    const int i1 = t & 63;
    const int half = (t >> 6) & 1;
    const int pq4 = (t >> 7) << 2;         // 0/4/8/12
    const int jbase = half * 48;
    // stage-2 identity: (j-lane, pixel-quad)
    const int jr = t & 127;                // active if < 96
    const int wv = t >> 6;                 // wave id; waves (2k,2k+1) pair on same pq
    const bool act = (jr < COUT);
    const int jrc = act ? jr : 0;

    // ---- one-time staging ----
    for (int k = t; k < CIN * COUT; k += NTHR)     // Wr <- w (coalesced)
        ((float*)Wr)[k] = w[k];
    for (int k = t; k < COUT * PPB; k += NTHR) {   // h init, transposed [j][p]
        const int j = k >> 4;
        const int p = k & 15;
        Hst[j][p] = h0[j];
    }

    // ---- one-time: W half-row -> wreg[48] (registers; 48 is safely promotable) ----
    float wreg[48];
    #pragma unroll
    for (int jj = 0; jj < 48; jj += 4) {
        const float4 v = *(const float4*)&w[i1 * COUT + jbase + jj];
        wreg[jj] = v.x; wreg[jj + 1] = v.y; wreg[jj + 2] = v.z; wreg[jj + 3] = v.w;
    }

    // x for this thread's 4 pixels (contiguous hw -> one float4)
    const float4 xv = *(const float4*)&x[((size_t)b * CIN + i1) * HW_ + hw0 + pq4];

    __syncthreads();

    #pragma unroll 1
    for (int it = 0; it < NITER; ++it) {
        // ---- stage 1: partial denom over this j-half, 4 pixels ----
        float a0 = 0.f, a1 = 0.f, a2 = 0.f, a3 = 0.f;
        #pragma unroll
        for (int jj = 0; jj < 48; ++jj) {
            const float4 hv = *(const float4*)&Hst[jbase + jj][pq4];  // uniform-addr b128 broadcast
            const float wj = wreg[jj];
            a0 += wj * hv.x; a1 += wj * hv.y; a2 += wj * hv.z; a3 += wj * hv.w;
        }
        *(float4*)&Dpart[half][i1][pq4] = make_float4(a0, a1, a2, a3);
        __syncthreads();   // Dpart ready

        // ---- combine halves, divide, write Tsp[i][p] ----
        if (half == 0) {
            const float4 o = *(const float4*)&Dpart[1][i1][pq4];
            float4 tw;
            tw.x = xv.x / ((a0 + o.x) + NMF_EPS);
            tw.y = xv.y / ((a1 + o.y) + NMF_EPS);
            tw.z = xv.z / ((a2 + o.z) + NMF_EPS);
            tw.w = xv.w / ((a3 + o.w) + NMF_EPS);
            *(float4*)&Tsp[i1][pq4] = tw;
        }
        __syncthreads();   // Tsp ready

        // ---- stage 2: u[px] = sum_i W[i][jr] * t[px][i] ----
        float u0 = 0.f, u1 = 0.f, u2 = 0.f, u3 = 0.f;
        #pragma unroll
        for (int i = 0; i < CIN; ++i) {
            const float wv_ = Wr[i][jrc];                       // stride-1, conflict-free
            const float4 tv = *(const float4*)&Tsp[i][pq4];     // uniform-addr b128 broadcast
            u0 += wv_ * tv.x; u1 += wv_ * tv.y;
            u2 += wv_ * tv.z; u3 += wv_ * tv.w;
        }
        const float4 hq = *(const float4*)&Hst[jrc][pq4];       // b128, lane-stride 5 quads
        float hp0 = 0.f, hp1 = 0.f, hp2 = 0.f, hp3 = 0.f;
        if (act) {
            hp0 = hq.x * (1.f + u0);
            hp1 = hq.y * (1.f + u1);
            hp2 = hq.z * (1.f + u2);
            hp3 = hq.w * (1.f + u3);
        }
        // ---- normalize over j: 64-lane tree + cross-wave pair ----
        float s0 = hp0, s1 = hp1, s2 = hp2, s3 = hp3;
        #pragma unroll
        for (int d = 32; d >= 1; d >>= 1) {
            s0 += __shfl_xor(s0, d, 64);
            s1 += __shfl_xor(s1, d, 64);
            s2 += __shfl_xor(s2, d, 64);
            s3 += __shfl_xor(s3, d, 64);
        }
        if ((t & 63) == 0) Par[wv] = make_float4(s0, s1, s2, s3);
        __syncthreads();   // Par ready
        const float4 other = Par[wv ^ 1];
        const float inv0 = 1.f / ((s0 + other.x) + NMF_EPS);
        const float inv1 = 1.f / ((s1 + other.y) + NMF_EPS);
        const float inv2 = 1.f / ((s2 + other.z) + NMF_EPS);
        const float inv3 = 1.f / ((s3 + other.w) + NMF_EPS);
        if (act) {
            *(float4*)&Hst[jr][pq4] =
                make_float4(hp0 * inv0, hp1 * inv1, hp2 * inv2, hp3 * inv3);
        }
        __syncthreads();   // Hst ready for next iteration
    }

    // ---- write h -> out (B, Cout, H, W) ----
    for (int k = t; k < COUT * PPB; k += NTHR) {
        const int j = k >> 4;
        const int p = k & 15;
        out[((size_t)b * COUT + j) * HW_ + hw0 + p] = Hst[j][p];
    }
}

extern "C" void kernel_launch(void* const* d_in, const int* in_sizes, int n_in,
                              void* d_out, int out_size, void* d_ws, size_t ws_size,
                              hipStream_t stream) {
    const float* x  = (const float*)d_in[0];
    const float* w  = (const float*)d_in[1];
    const float* h0 = (const float*)d_in[2];
    float* out = (float*)d_out;
    nmf_kernel<<<256, NTHR, 0, stream>>>(x, w, h0, out);
}